// Round 4
// baseline (93.732 us; speedup 1.0000x reference)
//
#include <hip/hip_runtime.h>

typedef __attribute__((ext_vector_type(8))) short short8;
typedef __attribute__((ext_vector_type(4))) float f32x4;
typedef __attribute__((ext_vector_type(4))) int   i32x4;

#define IN_F   4096
#define OUT_F  16384
#define B_ROWS 32
#define NG     32           // scale groups per row
#define BK     256          // ints per K-chunk (= 2 scale groups of 128)
#define NCHUNK (IN_F / BK)  // 16
#define BN     32           // qw rows (output cols) per block

// f32 -> bf16 round-to-nearest-even
static __device__ __forceinline__ short f2bf(float f) {
    union { float f; unsigned u; } c; c.f = f;
    unsigned u = c.u;
    u += 0x7FFF + ((u >> 16) & 1);
    return (short)(u >> 16);
}

// int8-range -> bf16 (exact for |v| <= 127)
static __device__ __forceinline__ short i2bf(int v) {
    union { float f; unsigned u; } c; c.f = (float)v;
    return (short)(c.u >> 16);
}

// Block: 256 thr = 4 waves. Block owns 32 output cols (qw rows), full K.
// Wave (wm,wn) owns the 16x16 output tile (rows 16wm.., cols 16wn..), full-K
// accumulation -> no cross-wave reduction. qw staged per-chunk via
// global_load_lds (1 KB contiguous per instruction), double-buffered.
// LDS read swizzle: linear dest + pre-swizzled global source + same XOR on
// ds_read address (rule: both-sides-or-neither).
__global__ __launch_bounds__(256, 4)
void qlin_kernel(const float* __restrict__ x,       // [32][4096] f32
                 const int*   __restrict__ qw,      // [16384][4096] int32 (int8 vals)
                 const float* __restrict__ scales,  // [16384][32] f32
                 const float* __restrict__ bias,    // [16384] f32
                 float*       __restrict__ out)     // [32][16384] f32
{
    __shared__ int lds_qw[2][BN][BK];               // 2 x 32 KB = 64 KB

    const int tid  = threadIdx.x;
    const int wv   = tid >> 6;        // wave 0..3
    const int lane = tid & 63;
    const int l15  = lane & 15;
    const int l4   = lane >> 4;       // 0..3
    const int wm   = wv >> 1;         // m-half (batch rows 16wm..)
    const int wn   = wv & 1;          // n-half (cols 16wn..)
    const int col0 = blockIdx.x * BN;

    // ---- staging: wave wv stages LDS rows [8wv, 8wv+8) of the chunk ----
    // per row: one global_load_lds of 1 KB; source byte offset per lane is
    // (lane*16) ^ ((row&7)<<4)  (row&7 == i since 8wv is 0 mod 8)
    const int swz_lane = lane * 16;
    auto STAGE = [&](int c, int b) {
#pragma unroll
        for (int i = 0; i < 8; ++i) {
            const int row = 8 * wv + i;
            const char* src = (const char*)(qw + (size_t)(col0 + row) * IN_F + c * BK)
                              + (swz_lane ^ (i << 4));
            __builtin_amdgcn_global_load_lds(
                (const __attribute__((address_space(1))) unsigned int*)src,
                (__attribute__((address_space(3))) unsigned int*)&lds_qw[b][row][0],
                16, 0, 0);
        }
    };

    // ---- compute one chunk from LDS buffer b ----
    const float* xr   = x + (size_t)(16 * wm + l15) * IN_F;   // A row (batch)
    const int    rowB = 16 * wn + l15;                        // LDS row (out col)
    const int    swzB = (rowB & 7) << 4;
    const float* scr  = scales + (size_t)(col0 + rowB) * NG;

    f32x4 acc = {0.f, 0.f, 0.f, 0.f};

    auto COMPUTE = [&](int c, int b) {
        const char* ldsrow = (const char*)&lds_qw[b][rowB][0];
#pragma unroll
        for (int g2 = 0; g2 < 2; ++g2) {           // two 128-int scale groups
            f32x4 ag = {0.f, 0.f, 0.f, 0.f};
#pragma unroll
            for (int s = 0; s < 4; ++s) {          // K-steps of 32
                const int kk = g2 * 128 + s * 32 + l4 * 8;  // int idx in chunk
                // A: x f32 -> bf16
                f32x4 x0 = *(const f32x4*)(xr + c * BK + kk);
                f32x4 x1 = *(const f32x4*)(xr + c * BK + kk + 4);
                short8 a;
#pragma unroll
                for (int j = 0; j < 4; ++j) { a[j] = f2bf(x0[j]); a[j + 4] = f2bf(x1[j]); }
                // B: swizzled ds_read of 8 ints, convert to bf16
                const int byte0 = (kk * 4) ^ swzB;
                const int byte1 = (kk * 4 + 16) ^ swzB;
                i32x4 q0 = *(const i32x4*)(ldsrow + byte0);
                i32x4 q1 = *(const i32x4*)(ldsrow + byte1);
                short8 bfr;
#pragma unroll
                for (int j = 0; j < 4; ++j) { bfr[j] = i2bf(q0[j]); bfr[j + 4] = i2bf(q1[j]); }
                ag = __builtin_amdgcn_mfma_f32_16x16x32_bf16(a, bfr, ag, 0, 0, 0);
            }
            const float sc = scr[c * 2 + g2];
#pragma unroll
            for (int r = 0; r < 4; ++r) acc[r] += sc * ag[r];
        }
    };

    // ---- pipelined chunk loop: stage(next) || compute(cur), 1 barrier/chunk ----
    STAGE(0, 0);
    __syncthreads();                  // compiler drains vmcnt(0) before barrier
    int cur = 0;
    for (int c = 0; c < NCHUNK - 1; ++c) {
        STAGE(c + 1, cur ^ 1);
        COMPUTE(c, cur);
        __syncthreads();
        cur ^= 1;
    }
    COMPUTE(NCHUNK - 1, cur);

    // ---- epilogue: direct store (wave owns full K) ----
    const int col = col0 + rowB;
    const float bv = bias[col];
#pragma unroll
    for (int r = 0; r < 4; ++r) {
        const int row = 16 * wm + l4 * 4 + r;
        out[(size_t)row * OUT_F + col] = acc[r] + bv;
    }
}

extern "C" void kernel_launch(void* const* d_in, const int* in_sizes, int n_in,
                              void* d_out, int out_size, void* d_ws, size_t ws_size,
                              hipStream_t stream) {
    const float* x      = (const float*)d_in[0];
    const int*   qw     = (const int*)d_in[1];
    const float* scales = (const float*)d_in[2];
    const float* bias   = (const float*)d_in[3];
    float*       out    = (float*)d_out;

    hipLaunchKernelGGL(qlin_kernel, dim3(OUT_F / BN), dim3(256), 0, stream,
                       x, qw, scales, bias, out);
}

// Round 5
// 57.448 us; speedup vs baseline: 1.6316x; 1.6316x over previous
//
#include <hip/hip_runtime.h>

typedef __attribute__((ext_vector_type(8))) short short8;
typedef __attribute__((ext_vector_type(4))) float f32x4;
typedef __attribute__((ext_vector_type(4))) int   i32x4;

#define IN_F   4096
#define OUT_F  16384
#define NG     32
#define BK     128          // ints per chunk (= one scale group)
#define NCHUNK 16           // chunks per K-half (2048/128)

// f32 -> bf16 round-to-nearest-even
static __device__ __forceinline__ short f2bf(float f) {
    union { float f; unsigned u; } c; c.f = f;
    unsigned u = c.u;
    u += 0x7FFF + ((u >> 16) & 1);
    return (short)(u >> 16);
}

// int8-range -> bf16 (exact for |v| <= 127)
static __device__ __forceinline__ short i2bf(int v) {
    union { float f; unsigned u; } c; c.f = (float)v;
    return (short)(c.u >> 16);
}

// Pre-pass: x[32][4096] f32 -> xT bf16 in MFMA-A-fragment order.
// xT layout: [t][h][ln][8] bf16, t = k-tile (k/32), h = m-half (rows 16h..),
// ln = l15*4 + l4. One thread per 16B output -> writes perfectly coalesced.
__global__ __launch_bounds__(256)
void xconv_kernel(const float* __restrict__ x, unsigned short* __restrict__ xT) {
    const int g   = blockIdx.x * 256 + threadIdx.x;   // 16384 threads
    const int t   = g >> 7;
    const int rem = g & 127;
    const int h   = rem >> 6;
    const int ln  = rem & 63;
    const int l15 = ln >> 2;
    const int l4  = ln & 3;
    const float* src = x + (size_t)(16 * h + l15) * IN_F + t * 32 + l4 * 8;
    f32x4 a = *(const f32x4*)src;
    f32x4 b = *(const f32x4*)(src + 4);
    short8 o;
#pragma unroll
    for (int j = 0; j < 4; ++j) { o[j] = f2bf(a[j]); o[j + 4] = f2bf(b[j]); }
    *(short8*)(xT + (size_t)g * 8) = o;
}

// Main: 512 thr = 8 waves. Block owns 32 out-cols. wk = wave K-half,
// (wm,wn) = 16x16 tile. qw staged coalesced via global_load_lds into
// XOR-swizzled double-buffered LDS; xT read direct (coalesced, L2-hot).
// Grid 512 -> 2 blocks/CU (LDS 72KB), 16 waves/CU.
__global__ __launch_bounds__(512, 4)
void qlin_kernel(const unsigned short* __restrict__ xT,  // fragment-ordered bf16
                 const int*   __restrict__ qw,           // [16384][4096] int32
                 const float* __restrict__ scales,       // [16384][32] f32
                 const float* __restrict__ bias,         // [16384] f32
                 float*       __restrict__ out)          // [32][16384] f32
{
    __shared__ int   lqw[2][2][32][BK];   // [wk][dbuf][row][int] = 64 KB
    __shared__ float red[8][64][4];       // 8 KB cross-wk reduce

    const int tid  = threadIdx.x;
    const int wv   = tid >> 6;
    const int lane = tid & 63;
    const int l15  = lane & 15;
    const int l4   = lane >> 4;
    const int wk   = wv >> 2;         // K-half
    const int wm   = (wv >> 1) & 1;   // m-half
    const int wn   = wv & 1;          // n-half
    const int col0 = blockIdx.x * 32;

    // stage chunk c of this wave's K-half into buffer b.
    // Each instr: 1 KB = 2 rows x 512B, lanes 0-31 row 2p, 32-63 row 2p+1.
    // Source pre-swizzled by ((row&7)<<4); LDS dest linear (rule #21).
    auto STAGE = [&](int c, int b) {
        const int widx = wv & 3;
        const size_t kbase = (size_t)wk * 2048 + (size_t)c * BK;
#pragma unroll
        for (int i = 0; i < 4; ++i) {
            const int p   = widx * 4 + i;
            const int row = 2 * p + (lane >> 5);
            const int byt = ((lane & 31) * 16) ^ ((row & 7) << 4);
            const char* src = (const char*)(qw + (size_t)(col0 + row) * IN_F + kbase) + byt;
            __builtin_amdgcn_global_load_lds(
                (const __attribute__((address_space(1))) unsigned int*)src,
                (__attribute__((address_space(3))) unsigned int*)&lqw[wk][b][2 * p][0],
                16, 0, 0);
        }
    };

    const int rowB = 16 * wn + l15;           // LDS row = out-col within block
    const int swzB = (rowB & 7) << 4;
    const char* lrow_base0 = (const char*)&lqw[wk][0][rowB][0];
    const char* lrow_base1 = (const char*)&lqw[wk][1][rowB][0];
    const unsigned short* xgrp = xT + (size_t)(l15 * 4 + l4) * 8 + (size_t)wm * 512;

    f32x4 acc = {0.f, 0.f, 0.f, 0.f};

    auto COMPUTE = [&](int c, int b) {
        const char* lrow = b ? lrow_base1 : lrow_base0;
        f32x4 ag = {0.f, 0.f, 0.f, 0.f};
#pragma unroll
        for (int s = 0; s < 4; ++s) {
            const int t = wk * 64 + c * 4 + s;            // global k-tile
            short8 a = *(const short8*)(xgrp + (size_t)t * 1024);
            const int byte0 = (s * 128 + l4 * 32) ^ swzB;
            i32x4 q0 = *(const i32x4*)(lrow + byte0);
            i32x4 q1 = *(const i32x4*)(lrow + (byte0 ^ 16));
            short8 bfr;
#pragma unroll
            for (int j = 0; j < 4; ++j) { bfr[j] = i2bf(q0[j]); bfr[j + 4] = i2bf(q1[j]); }
            ag = __builtin_amdgcn_mfma_f32_16x16x32_bf16(a, bfr, ag, 0, 0, 0);
        }
        const float sc = scales[(size_t)(col0 + rowB) * NG + wk * 16 + c];
#pragma unroll
        for (int r = 0; r < 4; ++r) acc[r] += sc * ag[r];
    };

    // 2-phase pipeline, 1 barrier per chunk
    STAGE(0, 0);
    __syncthreads();
    int cur = 0;
    for (int c = 0; c < NCHUNK - 1; ++c) {
        STAGE(c + 1, cur ^ 1);
        COMPUTE(c, cur);
        __syncthreads();
        cur ^= 1;
    }
    COMPUTE(NCHUNK - 1, cur);

    // cross-wk reduce + bias + store
#pragma unroll
    for (int r = 0; r < 4; ++r) red[wv][lane][r] = acc[r];
    __syncthreads();
    if (wv < 4) {
        const int col = col0 + rowB;
        const float bv = bias[col];
#pragma unroll
        for (int r = 0; r < 4; ++r) {
            const float v = red[wv][lane][r] + red[wv + 4][lane][r] + bv;
            out[(size_t)(16 * wm + l4 * 4 + r) * OUT_F + col] = v;
        }
    }
}

extern "C" void kernel_launch(void* const* d_in, const int* in_sizes, int n_in,
                              void* d_out, int out_size, void* d_ws, size_t ws_size,
                              hipStream_t stream) {
    const float* x      = (const float*)d_in[0];
    const int*   qw     = (const int*)d_in[1];
    const float* scales = (const float*)d_in[2];
    const float* bias   = (const float*)d_in[3];
    float*       out    = (float*)d_out;
    unsigned short* xT  = (unsigned short*)d_ws;   // 256 KB fragment-ordered x

    hipLaunchKernelGGL(xconv_kernel, dim3(64), dim3(256), 0, stream, x, xT);
    hipLaunchKernelGGL(qlin_kernel, dim3(OUT_F / 32), dim3(512), 0, stream,
                       xT, qw, scales, bias, out);
}

// Round 6
// 52.611 us; speedup vs baseline: 1.7816x; 1.0919x over previous
//
#include <hip/hip_runtime.h>

typedef __attribute__((ext_vector_type(8))) short short8;
typedef __attribute__((ext_vector_type(4))) float f32x4;
typedef __attribute__((ext_vector_type(4))) int   i32x4;

#define IN_F   4096
#define OUT_F  16384
#define NG     32
#define BK     64           // ints per chunk
#define NCH    32           // chunks per K-half (2048/64)

// f32 -> bf16 round-to-nearest-even
static __device__ __forceinline__ short f2bf(float f) {
    union { float f; unsigned u; } c; c.f = f;
    unsigned u = c.u;
    u += 0x7FFF + ((u >> 16) & 1);
    return (short)(u >> 16);
}

// int8-range -> bf16 (exact for |v| <= 127)
static __device__ __forceinline__ short i2bf(int v) {
    union { float f; unsigned u; } c; c.f = (float)v;
    return (short)(c.u >> 16);
}

// Pre-pass: x[32][4096] f32 -> xT bf16 in MFMA-A-fragment order.
// xT layout: [t][h][ln][8] bf16, t = k/32, h = m-half, ln = l15*4 + l4.
__global__ __launch_bounds__(256)
void xconv_kernel(const float* __restrict__ x, unsigned short* __restrict__ xT) {
    const int g   = blockIdx.x * 256 + threadIdx.x;   // 16384 threads
    const int t   = g >> 7;
    const int rem = g & 127;
    const int h   = rem >> 6;
    const int ln  = rem & 63;
    const int l15 = ln >> 2;
    const int l4  = ln & 3;
    const float* src = x + (size_t)(16 * h + l15) * IN_F + t * 32 + l4 * 8;
    f32x4 a = *(const f32x4*)src;
    f32x4 b = *(const f32x4*)(src + 4);
    short8 o;
#pragma unroll
    for (int j = 0; j < 4; ++j) { o[j] = f2bf(a[j]); o[j + 4] = f2bf(b[j]); }
    *(short8*)(xT + (size_t)g * 8) = o;
}

// Main: 512 thr = 8 waves, block owns 32 out-cols, wk = K-half, (wm,wn) tile.
// Counted-vmcnt pipeline: 3 LDS slots, stage chunk i+2 while computing i,
// s_waitcnt vmcnt(4) (never 0 in steady state) + raw s_barrier.
__global__ __launch_bounds__(512, 4)
void qlin_kernel(const unsigned short* __restrict__ xT,
                 const int*   __restrict__ qw,
                 const float* __restrict__ scales,
                 const float* __restrict__ bias,
                 float*       __restrict__ out)
{
    __shared__ int lqw[2][3][32][BK];   // 48 KB; aliased as `red` in epilogue

    const int tid  = threadIdx.x;
    const int wv   = tid >> 6;
    const int lane = tid & 63;
    const int l15  = lane & 15;
    const int l4   = lane >> 4;
    const int wk   = wv >> 2;         // K-half
    const int wm   = (wv >> 1) & 1;   // m-half
    const int wn   = wv & 1;          // n-half
    const int widx = wv & 3;
    const int col0 = blockIdx.x * 32;

    const int rowB = 16 * wn + l15;
    const int swzB = (rowB & 7) << 4;

    // --- stage chunk c (of this wave's K-half) into slot sl ---
    // 8 instrs per wk-group (2/wave), each 1 KB = 4 rows x 256 B linear LDS;
    // global source pre-swizzled by ((row&7)<<4) (rule: both-sides-or-neither).
    auto STAGE = [&](int c, int sl) {
        const size_t kbase = (size_t)wk * 2048 + (size_t)c * BK;
#pragma unroll
        for (int i = 0; i < 2; ++i) {
            const int p   = widx * 2 + i;            // 0..7
            const int row = 4 * p + (lane >> 4);
            const int byt = ((lane & 15) * 16) ^ ((row & 7) << 4);
            const char* src = (const char*)(qw + (size_t)(col0 + row) * IN_F + kbase) + byt;
            __builtin_amdgcn_global_load_lds(
                (const __attribute__((address_space(1))) unsigned int*)src,
                (__attribute__((address_space(3))) unsigned int*)&lqw[wk][sl][4 * p][0],
                16, 0, 0);
        }
    };

    // --- x fragments: prefetch to registers, distance 2 ---
    const unsigned short* xgrp = xT + (size_t)(l15 * 4 + l4) * 8 + (size_t)wm * 512;
    short8 xa[2][2];                   // [parity][step]
    auto XLOAD = [&](int c, int par) {
        const int t = wk * 64 + c * 2;
        xa[par][0] = *(const short8*)(xgrp + (size_t)t * 1024);
        xa[par][1] = *(const short8*)(xgrp + (size_t)(t + 1) * 1024);
    };

    // --- scales: all 16 groups of this wave's K-half, preloaded ---
    const float* scr = scales + (size_t)(col0 + rowB) * NG + wk * 16;
    f32x4 sc4[4];
#pragma unroll
    for (int j = 0; j < 4; ++j) sc4[j] = *(const f32x4*)(scr + 4 * j);

    f32x4 acc = {0.f, 0.f, 0.f, 0.f};

    // --- compute chunk c from slot sl, x parity par (all indices static) ---
    auto COMPUTE = [&](int c, int sl, int par, float sc) {
        const char* lrow = (const char*)&lqw[wk][sl][rowB][0];
        f32x4 ag = {0.f, 0.f, 0.f, 0.f};
#pragma unroll
        for (int s = 0; s < 2; ++s) {
            const int byte0 = (s * 128 + l4 * 32) ^ swzB;
            i32x4 q0 = *(const i32x4*)(lrow + byte0);
            i32x4 q1 = *(const i32x4*)(lrow + (byte0 ^ 16));
            short8 bfr;
#pragma unroll
            for (int j = 0; j < 4; ++j) { bfr[j] = i2bf(q0[j]); bfr[j + 4] = i2bf(q1[j]); }
            ag = __builtin_amdgcn_mfma_f32_16x16x32_bf16(xa[par][s], bfr, ag, 0, 0, 0);
        }
#pragma unroll
        for (int r = 0; r < 4; ++r) acc[r] += sc * ag[r];
    };

    // --- prologue: x(0),x(1) then qw(0),qw(1); wait qw(0) (vmcnt(2) keeps qw(1)) ---
    XLOAD(0, 0);
    XLOAD(1, 1);
    asm volatile("" ::: "memory");     // pin: x-loads issue before stages
    STAGE(0, 0);
    STAGE(1, 1);
    asm volatile("s_waitcnt vmcnt(2)" ::: "memory");
    __builtin_amdgcn_s_barrier();
    __builtin_amdgcn_sched_barrier(0);

    // --- steady state: compute(i) || {x(i+2), qw(i+2)} in flight; vmcnt(4) ---
#pragma unroll
    for (int i = 0; i <= 29; ++i) {
        COMPUTE(i, i % 3, i & 1, sc4[(i >> 3)][(i >> 1) & 3]);
        XLOAD(i + 2, i & 1);
        asm volatile("" ::: "memory");
        STAGE(i + 2, (i + 2) % 3);
        asm volatile("s_waitcnt vmcnt(4)" ::: "memory");
        __builtin_amdgcn_s_barrier();
        __builtin_amdgcn_sched_barrier(0);
    }
    COMPUTE(30, 0, 0, sc4[3][3]);
    asm volatile("s_waitcnt vmcnt(0)" ::: "memory");
    __builtin_amdgcn_s_barrier();
    __builtin_amdgcn_sched_barrier(0);
    COMPUTE(31, 1, 1, sc4[3][3]);

    // --- epilogue: cross-wk reduce through aliased LDS ---
    __syncthreads();
    float* red = (float*)&lqw[0][0][0][0];    // [8][64][4] = 8 KB
    *(f32x4*)&red[(size_t)(wv * 64 + lane) * 4] = acc;
    __syncthreads();
    if (wv < 4) {
        const int col = col0 + rowB;
        const float bv = bias[col];
        f32x4 lo = *(const f32x4*)&red[(size_t)(wv * 64 + lane) * 4];
        f32x4 hi = *(const f32x4*)&red[(size_t)((wv + 4) * 64 + lane) * 4];
#pragma unroll
        for (int r = 0; r < 4; ++r)
            out[(size_t)(16 * wm + l4 * 4 + r) * OUT_F + col] = lo[r] + hi[r] + bv;
    }
}

extern "C" void kernel_launch(void* const* d_in, const int* in_sizes, int n_in,
                              void* d_out, int out_size, void* d_ws, size_t ws_size,
                              hipStream_t stream) {
    const float* x      = (const float*)d_in[0];
    const int*   qw     = (const int*)d_in[1];
    const float* scales = (const float*)d_in[2];
    const float* bias   = (const float*)d_in[3];
    float*       out    = (float*)d_out;
    unsigned short* xT  = (unsigned short*)d_ws;   // 256 KB fragment-ordered x

    hipLaunchKernelGGL(xconv_kernel, dim3(64), dim3(256), 0, stream, x, xT);
    hipLaunchKernelGGL(qlin_kernel, dim3(OUT_F / 32), dim3(512), 0, stream,
                       xT, qw, scales, bias, out);
}